// Round 5
// baseline (162.918 us; speedup 1.0000x reference)
//
#include <hip/hip_runtime.h>

#define BB 2
#define SS 2048
#define DD 1024
#define HH 16
#define HDIM 64
#define MTOT 4096  // B*S

typedef unsigned short u16;
typedef __bf16 bf16_t;
typedef bf16_t bf16x8 __attribute__((ext_vector_type(8)));
typedef float floatx4 __attribute__((ext_vector_type(4)));
typedef float floatx16 __attribute__((ext_vector_type(16)));

__device__ __forceinline__ float bf2f(u16 u) {
  union { unsigned int i; float f; } x;
  x.i = ((unsigned int)u) << 16;
  return x.f;
}
// round-to-nearest-even f32 -> bf16 (finite inputs only)
__device__ __forceinline__ u16 f2bf(float f) {
  union { float f; unsigned int i; } x;
  x.f = f;
  unsigned int r = x.i + 0x7fffu + ((x.i >> 16) & 1u);
  return (u16)(r >> 16);
}

// async global->LDS, 16B per lane. LDS dest = wave-uniform base + lane*16.
__device__ __forceinline__ void gload16(const u16* g, u16* l) {
  __builtin_amdgcn_global_load_lds(
      (const __attribute__((address_space(1))) unsigned int*)g,
      (__attribute__((address_space(3))) unsigned int*)l, 16, 0, 0);
}

// ---------------- kernel 1: fp32 -> bf16 cast of hs, Wq, Wk, Wv ----------------
__global__ __launch_bounds__(256) void cast_to_bf16(
    const float* __restrict__ hs, const float* __restrict__ wq,
    const float* __restrict__ wk, const float* __restrict__ wv,
    u16* __restrict__ hs_b, u16* __restrict__ wq_b,
    u16* __restrict__ wk_b, u16* __restrict__ wv_b) {
  int fid = blockIdx.x * 256 + threadIdx.x;  // 0 .. 1835007
  const float* src;
  u16* dst;
  int local;
  if (fid < 1048576) { src = hs; dst = hs_b; local = fid; }
  else if (fid < 1310720) { src = wq; dst = wq_b; local = fid - 1048576; }
  else if (fid < 1572864) { src = wk; dst = wk_b; local = fid - 1310720; }
  else { src = wv; dst = wv_b; local = fid - 1572864; }
  float4 v = reinterpret_cast<const float4*>(src)[local];
  ushort4 o;
  o.x = f2bf(v.x); o.y = f2bf(v.y); o.z = f2bf(v.z); o.w = f2bf(v.w);
  reinterpret_cast<ushort4*>(dst)[local] = o;
}

// ---------------- kernel 2: fused QKV projection, 128x128/BK64, 3-buf counted-vmcnt ----------------
// C[m,n] = sum_k A[m,k]*W[n,k] + bias[n].  A [4096,1024] bf16, W [1024,1024] bf16 (B^T).
// Round-5 design from round-4 post-mortem:
//  - grid 768 (3 seg x 32 mt x 8 nt) = 3 balanced blocks/CU, 100% CU coverage (r4: 192 blocks/75%).
//  - T3+T4 genuinely: 3-buffer LDS, stage tile t+2 at top of tile t, end-of-tile wait is
//    s_waitcnt vmcnt(4) (t+1 landed, t+2's 4 loads STAY IN FLIGHT) -- never 0 in main loop.
//    One raw s_barrier per K-tile (no compiler vmcnt(0) drains).
//  - 32x32x16 MFMA (r0's verified layout): epilogue stores 64 B-contiguous per 32-lane group
//    (r4's 16x16 epilogue caused WRITE_SIZE 27->61 MB RMW amplification).
//  - r4's proven 0-conflict slot swizzle: source col slot^(row&7), LDS linear, read re-XOR.
// 8 waves (2/SIMD TLP), wave tile 64x32 (2 M-frags x 1 N-frag), acc 32 VGPR.
__global__ __launch_bounds__(512, 2) void qkv_gemm_p3(
    const u16* __restrict__ A,
    const u16* __restrict__ Wq, const u16* __restrict__ Wk, const u16* __restrict__ Wv,
    const float* __restrict__ bq, const float* __restrict__ bk, const float* __restrict__ bv,
    u16* __restrict__ Qo, u16* __restrict__ Ko, u16* __restrict__ Vo) {
  __shared__ u16 sA[3][128 * 64];  // 3 x 16 KiB
  __shared__ u16 sB[3][128 * 64];  // 3 x 16 KiB   (total 96 KiB -> 1 block/CU)
  const int id = blockIdx.x;              // 0..767
  const int seg = id >> 8, rem = id & 255;
  const int mt = rem >> 3, nt = rem & 7;  // 32 x 8
  const u16* Wp = (seg == 0) ? Wq : (seg == 1) ? Wk : Wv;
  const float* bp = (seg == 0) ? bq : (seg == 1) ? bk : bv;
  u16* Out = (seg == 0) ? Qo : (seg == 1) ? Ko : Vo;
  const int m0 = mt * 128, n0 = nt * 128;
  const int tid = threadIdx.x;
  const int lane = tid & 63, wave = tid >> 6;
  const int l32 = lane & 31, khalf = lane >> 5;
  const int wm = (wave >> 2) * 64;  // 2 m-groups of 64
  const int wn = (wave & 3) * 32;   // 4 n-groups of 32

  // staging: 2 chunks x 512 thr cover 1024 (row,slot) 16B-cells per matrix; LDS lane-linear.
  int srow[2], sgc[2], soff[2];
#pragma unroll
  for (int c = 0; c < 2; ++c) {
    int L = c * 512 + tid;                    // 0..1023
    srow[c] = L >> 3;                         // 0..127
    sgc[c] = ((L & 7) ^ (srow[c] & 7)) << 3;  // swizzled global col (elements)
    soff[c] = L << 3;                         // L*8 u16 = L*16 B, linear
  }

#define STAGE(buf, kbase)                                                  \
  {                                                                        \
    _Pragma("unroll") for (int c = 0; c < 2; ++c) {                        \
      gload16(A + (size_t)(m0 + srow[c]) * DD + (kbase) + sgc[c],          \
              &sA[buf][soff[c]]);                                          \
      gload16(Wp + (size_t)(n0 + srow[c]) * DD + (kbase) + sgc[c],         \
              &sB[buf][soff[c]]);                                          \
    }                                                                      \
  }

  floatx16 acc[2] = {};
  STAGE(0, 0);
  STAGE(1, 64);
  asm volatile("s_waitcnt vmcnt(4)" ::: "memory");  // buf0 landed; buf1's 4 in flight
  __builtin_amdgcn_s_barrier();

  int cur = 0;
  for (int t = 0; t < 16; ++t) {
    if (t < 14) {
      const int nb = (cur >= 1) ? cur - 1 : 2;  // (t+2)%3
      STAGE(nb, (t + 2) * 64);
    }
    const u16* pA = sA[cur];
    const u16* pB = sB[cur];
#pragma unroll
    for (int ks = 0; ks < 4; ++ks) {
      // slot for k-halves: rows of A/B frags all share row&7 == l32&7
      const int sw = (((ks * 2 + khalf) ^ (l32 & 7)) << 3);
      bf16x8 b = *reinterpret_cast<const bf16x8*>(pB + (wn + l32) * 64 + sw);
      bf16x8 a0 = *reinterpret_cast<const bf16x8*>(pA + (wm + l32) * 64 + sw);
      bf16x8 a1 = *reinterpret_cast<const bf16x8*>(pA + (wm + 32 + l32) * 64 + sw);
      acc[0] = __builtin_amdgcn_mfma_f32_32x32x16_bf16(a0, b, acc[0], 0, 0, 0);
      acc[1] = __builtin_amdgcn_mfma_f32_32x32x16_bf16(a1, b, acc[1], 0, 0, 0);
    }
    // counted drain: t+1's 4 loads complete, t+2's 4 remain in flight (T4: never 0 mid-loop)
    if (t < 14) asm volatile("s_waitcnt vmcnt(4)" ::: "memory");
    else if (t == 14) asm volatile("s_waitcnt vmcnt(0)" ::: "memory");
    if (t < 15) __builtin_amdgcn_s_barrier();
    cur = (cur < 2) ? cur + 1 : 0;
  }
#undef STAGE

  // epilogue: 32x32 C/D layout col=lane&31, row=(reg&3)+8*(reg>>2)+4*khalf -> 64 B segments
  const int col = n0 + wn + l32;
  const float bias = bp[col];
#pragma unroll
  for (int i = 0; i < 2; ++i) {
#pragma unroll
    for (int reg = 0; reg < 16; ++reg) {
      int row = m0 + wm + i * 32 + (reg & 3) + 8 * (reg >> 2) + 4 * khalf;
      Out[(size_t)row * DD + col] = f2bf(acc[i][reg] + bias);
    }
  }
}

// ---------------- kernel 3: mpart[pc][bh][d][e] = sum_{s in chunk pc} mask[s]*V[s,d]*K[s,e] ----------------
// grid (32 chunks of 64 s-rows, 32 bh) = 1024 blocks -> 4 blocks/CU.
__global__ __launch_bounds__(256) void m_partial_kernel(
    const u16* __restrict__ Xb, const u16* __restrict__ Yb,
    const float* __restrict__ am, float* __restrict__ mpart) {
  __shared__ float sX[64 * 68];
  __shared__ float sY[64 * 68];
  const int bh = blockIdx.y;     // 0..31
  const int b = bh >> 4, h = bh & 15;
  const int tid = threadIdx.x;
  const int e0 = (tid & 15) * 4, d0 = (tid >> 4) * 4;
  const int s0 = blockIdx.x * 64;
  float acc[4][4] = {};
#pragma unroll
  for (int c = 0; c < 2; ++c) {
    int L = tid + c * 256;
    int srow = L >> 3;            // 0..63
    int col = (L & 7) * 8;        // 0..56
    size_t g = (size_t)(b * SS + s0 + srow) * DD + h * HDIM + col;
    uint4 xraw = *reinterpret_cast<const uint4*>(Xb + g);
    uint4 yraw = *reinterpret_cast<const uint4*>(Yb + g);
    float m = (am[b * SS + s0 + srow] >= 0.f) ? 1.f : 0.f;
    unsigned int xw[4] = {xraw.x, xraw.y, xraw.z, xraw.w};
    unsigned int yw[4] = {yraw.x, yraw.y, yraw.z, yraw.w};
#pragma unroll
    for (int q = 0; q < 4; ++q) {
      sX[srow * 68 + col + 2 * q]     = m * bf2f((u16)(xw[q] & 0xffffu));
      sX[srow * 68 + col + 2 * q + 1] = m * bf2f((u16)(xw[q] >> 16));
      sY[srow * 68 + col + 2 * q]     = bf2f((u16)(yw[q] & 0xffffu));
      sY[srow * 68 + col + 2 * q + 1] = bf2f((u16)(yw[q] >> 16));
    }
  }
  __syncthreads();
  for (int s = 0; s < 64; ++s) {
    float4 xx = *reinterpret_cast<const float4*>(&sX[s * 68 + e0]);
    float4 yy = *reinterpret_cast<const float4*>(&sY[s * 68 + d0]);
    float xa[4] = {xx.x, xx.y, xx.z, xx.w};
    float ya[4] = {yy.x, yy.y, yy.z, yy.w};
#pragma unroll
    for (int i = 0; i < 4; ++i)
#pragma unroll
      for (int j = 0; j < 4; ++j) acc[i][j] += xa[i] * ya[j];
  }
  float* outp = mpart + ((size_t)(blockIdx.x * 32 + bh)) * 4096;
#pragma unroll
  for (int i = 0; i < 4; ++i) {
    float4 o = {acc[i][0], acc[i][1], acc[i][2], acc[i][3]};
    *reinterpret_cast<float4*>(&outp[(e0 + i) * 64 + d0]) = o;
  }
}

// ---------------- kernel 4: reduce 32 partials -> M^T bf16 [32 bh][64*64] ----------------
__global__ __launch_bounds__(128) void m_reduce_kernel(
    const float* __restrict__ mpart, u16* __restrict__ Mb) {
  int t = blockIdx.x * 128 + threadIdx.x;  // 0..32767
  const float* p = mpart + (size_t)t * 4;
  float4 s = {0.f, 0.f, 0.f, 0.f};
#pragma unroll
  for (int pc = 0; pc < 32; ++pc) {
    float4 v = *reinterpret_cast<const float4*>(p + (size_t)pc * 131072);
    s.x += v.x; s.y += v.y; s.z += v.z; s.w += v.w;
  }
  ushort4 o = {f2bf(s.x), f2bf(s.y), f2bf(s.z), f2bf(s.w)};
  *reinterpret_cast<ushort4*>(Mb + (size_t)t * 4) = o;
}

// ---------------- kernel 5: ctx[m, h*64+d] = sum_e Q[m, h*64+e] * M[e,d]  (MFMA) ----------------
__global__ __launch_bounds__(256) void ctx_kernel(
    const u16* __restrict__ Qb, const u16* __restrict__ Mb, float* __restrict__ Out) {
  __shared__ u16 sMT[64 * 72];
  const int m0 = blockIdx.x * 128;
  const int h = blockIdx.y;
  const int b = m0 >> 11;         // 128-row tiles never cross the batch boundary
  const int bh = b * HH + h;
  const int tid = threadIdx.x;
  const u16* mg = Mb + (size_t)bh * 4096;
#pragma unroll
  for (int c = 0; c < 2; ++c) {
    int L = c * 256 + tid;        // 512 x 8 elems = 64x64
    int d = L >> 3, e = (L & 7) * 8;
    *reinterpret_cast<uint4*>(&sMT[d * 72 + e]) =
        *reinterpret_cast<const uint4*>(&mg[d * 64 + e]);
  }
  __syncthreads();
  const int lane = tid & 63, wave = tid >> 6;
  const int l32 = lane & 31, khalf = lane >> 5;
  const int arow = m0 + wave * 32 + l32;
  const u16* qrow = Qb + (size_t)arow * DD + h * HDIM + khalf * 8;
  bf16x8 af[4], bfr[2][4];
#pragma unroll
  for (int k0 = 0; k0 < 4; ++k0) {
    af[k0] = *reinterpret_cast<const bf16x8*>(qrow + k0 * 16);
#pragma unroll
    for (int j = 0; j < 2; ++j)
      bfr[j][k0] = *reinterpret_cast<const bf16x8*>(
          &sMT[(j * 32 + l32) * 72 + k0 * 16 + khalf * 8]);
  }
  floatx16 acc[2] = {};
#pragma unroll
  for (int j = 0; j < 2; ++j)
#pragma unroll
    for (int k0 = 0; k0 < 4; ++k0)
      acc[j] = __builtin_amdgcn_mfma_f32_32x32x16_bf16(af[k0], bfr[j][k0], acc[j], 0, 0, 0);
  // C/D layout: col = lane&31, row = (reg&3)+8*(reg>>2)+4*khalf
#pragma unroll
  for (int j = 0; j < 2; ++j) {
    int col = h * HDIM + j * 32 + l32;
#pragma unroll
    for (int reg = 0; reg < 16; ++reg) {
      int r = m0 + wave * 32 + (reg & 3) + 8 * (reg >> 2) + 4 * khalf;
      Out[(size_t)r * DD + col] = acc[j][reg];
    }
  }
}

extern "C" void kernel_launch(void* const* d_in, const int* in_sizes, int n_in,
                              void* d_out, int out_size, void* d_ws, size_t ws_size,
                              hipStream_t stream) {
  const float* hs = (const float*)d_in[0];
  const float* am = (const float*)d_in[1];
  const float* wq = (const float*)d_in[2];
  const float* bq = (const float*)d_in[3];
  const float* wk = (const float*)d_in[4];
  const float* bk = (const float*)d_in[5];
  const float* wv = (const float*)d_in[6];
  const float* bv = (const float*)d_in[7];
  float* out = (float*)d_out;
  char* ws = (char*)d_ws;

  // workspace layout (bytes), all 16B-aligned; total ~54.5 MB
  u16* hs_b = (u16*)(ws);                  // 8 MiB  [4096,1024] bf16
  u16* wq_b = (u16*)(ws + 8388608);        // 2 MiB
  u16* wk_b = (u16*)(ws + 10485760);       // 2 MiB
  u16* wv_b = (u16*)(ws + 12582912);       // 2 MiB
  u16* q_b  = (u16*)(ws + 14680064);       // 8 MiB
  u16* k_b  = (u16*)(ws + 23068672);       // 8 MiB
  u16* v_b  = (u16*)(ws + 31457280);       // 8 MiB
  float* mpart = (float*)(ws + 39845888);  // 16 MiB [32 pc][32 bh][64][64] f32 (M^T partials)
  u16* m_b  = (u16*)(ws + 56623104);       // 256 KiB [32 bh][64*64] bf16 (M^T)

  cast_to_bf16<<<7168, 256, 0, stream>>>(hs, wq, wk, wv, hs_b, wq_b, wk_b, wv_b);
  qkv_gemm_p3<<<768, 512, 0, stream>>>(hs_b, wq_b, wk_b, wv_b,
                                       bq, bk, bv, q_b, k_b, v_b);
  // X=V, Y=K -> partials hold M^T
  m_partial_kernel<<<dim3(32, 32), 256, 0, stream>>>(v_b, k_b, am, mpart);
  m_reduce_kernel<<<256, 128, 0, stream>>>(mpart, m_b);
  ctx_kernel<<<dim3(32, 16), 256, 0, stream>>>(q_b, m_b, out);
}

// Round 6
// 153.545 us; speedup vs baseline: 1.0610x; 1.0610x over previous
//
#include <hip/hip_runtime.h>

#define BB 2
#define SS 2048
#define DD 1024
#define HH 16
#define HDIM 64
#define MTOT 4096  // B*S

typedef unsigned short u16;
typedef __bf16 bf16_t;
typedef bf16_t bf16x8 __attribute__((ext_vector_type(8)));
typedef float floatx4 __attribute__((ext_vector_type(4)));
typedef float floatx16 __attribute__((ext_vector_type(16)));

__device__ __forceinline__ float bf2f(u16 u) {
  union { unsigned int i; float f; } x;
  x.i = ((unsigned int)u) << 16;
  return x.f;
}
// round-to-nearest-even f32 -> bf16 (finite inputs only)
__device__ __forceinline__ u16 f2bf(float f) {
  union { float f; unsigned int i; } x;
  x.f = f;
  unsigned int r = x.i + 0x7fffu + ((x.i >> 16) & 1u);
  return (u16)(r >> 16);
}

// async global->LDS, 16B per lane. LDS dest = wave-uniform base + lane*16.
__device__ __forceinline__ void gload16(const u16* g, u16* l) {
  __builtin_amdgcn_global_load_lds(
      (const __attribute__((address_space(1))) unsigned int*)g,
      (__attribute__((address_space(3))) unsigned int*)l, 16, 0, 0);
}

// ---------------- kernel 1: fp32 -> bf16 cast of hs, Wq, Wk, Wv ----------------
__global__ __launch_bounds__(256) void cast_to_bf16(
    const float* __restrict__ hs, const float* __restrict__ wq,
    const float* __restrict__ wk, const float* __restrict__ wv,
    u16* __restrict__ hs_b, u16* __restrict__ wq_b,
    u16* __restrict__ wk_b, u16* __restrict__ wv_b) {
  int fid = blockIdx.x * 256 + threadIdx.x;  // 0 .. 1835007
  const float* src;
  u16* dst;
  int local;
  if (fid < 1048576) { src = hs; dst = hs_b; local = fid; }
  else if (fid < 1310720) { src = wq; dst = wq_b; local = fid - 1048576; }
  else if (fid < 1572864) { src = wk; dst = wk_b; local = fid - 1310720; }
  else { src = wv; dst = wv_b; local = fid - 1572864; }
  float4 v = reinterpret_cast<const float4*>(src)[local];
  ushort4 o;
  o.x = f2bf(v.x); o.y = f2bf(v.y); o.z = f2bf(v.z); o.w = f2bf(v.w);
  reinterpret_cast<ushort4*>(dst)[local] = o;
}

// ---------------- kernel 2: fused QKV projection (r0 structure, BK=64) ----------------
// C[m,n] = sum_k A[m,k]*W[n,k] + bias[n].  A [4096,1024] bf16, W [1024,1024] bf16 (B^T).
// EXACT round-0 barrier structure (stage -> __syncthreads -> compute -> __syncthreads),
// known-good grid dim3(24,32) ordering (FETCH ~36 MB). Only changes vs r0:
//  - BK 32 -> 64: 16 K-iterations instead of 32 -> HALF the vmcnt(0) drain events,
//    which the r5 post-mortem model identifies as the per-block cost driver.
//    LDS 2 x 16 KiB = 32 KiB -> same ~3 blocks/CU occupancy as r0 (m132's BK=128
//    regression was the 64 KiB occupancy cliff; 32 KiB stays clear).
//  - 8-slot source swizzle slot^(row&7) (r5 measured: halves bank conflicts; r2's
//    4-slot version couldn't cover the 8 bank-quads of a 128 B row).
#define BKK 64
__global__ __launch_bounds__(256) void qkv_gemm_kernel(
    const u16* __restrict__ A,
    const u16* __restrict__ Wq, const u16* __restrict__ Wk, const u16* __restrict__ Wv,
    const float* __restrict__ bq, const float* __restrict__ bk, const float* __restrict__ bv,
    u16* __restrict__ Qo, u16* __restrict__ Ko, u16* __restrict__ Vo) {
  __shared__ u16 sA[128 * BKK];  // 16 KiB
  __shared__ u16 sB[128 * BKK];  // 16 KiB
  const int mt = blockIdx.y, ntall = blockIdx.x;
  const int seg = ntall >> 3, nt = ntall & 7;
  const u16* Wp = (seg == 0) ? Wq : (seg == 1) ? Wk : Wv;
  const float* bp = (seg == 0) ? bq : (seg == 1) ? bk : bv;
  u16* Out = (seg == 0) ? Qo : (seg == 1) ? Ko : Vo;
  const int m0 = mt * 128, n0 = nt * 128;
  const int tid = threadIdx.x;
  const int lane = tid & 63, wave = tid >> 6;
  const int wm = (wave >> 1) * 64, wn = (wave & 1) * 64;
  const int l32 = lane & 31, khalf = lane >> 5;
  // staging: 4 passes x 256 thr x 16 B cover 128x64 u16 per matrix; LDS lane-linear.
  int srow[4], sgc[4], soff[4];
#pragma unroll
  for (int c = 0; c < 4; ++c) {
    int L = c * 256 + tid;                    // 0..1023
    srow[c] = L >> 3;                         // 0..127
    sgc[c] = ((L & 7) ^ (srow[c] & 7)) << 3;  // swizzled source col (elements)
    soff[c] = L << 3;                         // L*8 u16 = 16 B cells, linear
  }
  floatx16 acc[2][2] = {};
  for (int k0 = 0; k0 < DD; k0 += BKK) {
#pragma unroll
    for (int c = 0; c < 4; ++c) {
      gload16(A + (size_t)(m0 + srow[c]) * DD + k0 + sgc[c], sA + soff[c]);
      gload16(Wp + (size_t)(n0 + srow[c]) * DD + k0 + sgc[c], sB + soff[c]);
    }
    __syncthreads();  // drains vmcnt(0) -> LDS tiles complete
#pragma unroll
    for (int kk = 0; kk < 4; ++kk) {
      const int sw = ((kk * 2 + khalf) ^ (l32 & 7)) << 3;  // re-XOR on read
      bf16x8 af[2], bfr[2];
#pragma unroll
      for (int i = 0; i < 2; ++i)
        af[i] = *reinterpret_cast<const bf16x8*>(sA + (wm + i * 32 + l32) * BKK + sw);
#pragma unroll
      for (int j = 0; j < 2; ++j)
        bfr[j] = *reinterpret_cast<const bf16x8*>(sB + (wn + j * 32 + l32) * BKK + sw);
#pragma unroll
      for (int i = 0; i < 2; ++i)
#pragma unroll
        for (int j = 0; j < 2; ++j)
          acc[i][j] = __builtin_amdgcn_mfma_f32_32x32x16_bf16(af[i], bfr[j], acc[i][j], 0, 0, 0);
    }
    __syncthreads();
  }
  // epilogue: C/D layout col=lane&31, row=(reg&3)+8*(reg>>2)+4*(lane>>5)
#pragma unroll
  for (int j = 0; j < 2; ++j) {
    int col = n0 + wn + j * 32 + l32;
    float bias = bp[col];
#pragma unroll
    for (int i = 0; i < 2; ++i) {
#pragma unroll
      for (int reg = 0; reg < 16; ++reg) {
        int row = m0 + wm + i * 32 + (reg & 3) + 8 * (reg >> 2) + 4 * khalf;
        Out[(size_t)row * DD + col] = f2bf(acc[i][j][reg] + bias);
      }
    }
  }
}

// ---------------- kernel 3: mpart[pc][bh][d][e] = sum_{s in chunk pc} mask[s]*V[s,d]*K[s,e] ----------------
// 16 chunks of 128 s-rows (2 sub-tiles of 64) x 32 bh = 512 blocks -> 2/CU.
__global__ __launch_bounds__(256) void m_partial_kernel(
    const u16* __restrict__ Xb, const u16* __restrict__ Yb,
    const float* __restrict__ am, float* __restrict__ mpart) {
  __shared__ float sX[64 * 68];
  __shared__ float sY[64 * 68];
  const int bh = blockIdx.y;     // 0..31
  const int b = bh >> 4, h = bh & 15;
  const int tid = threadIdx.x;
  const int e0 = (tid & 15) * 4, d0 = (tid >> 4) * 4;
  float acc[4][4] = {};
  for (int cs = 0; cs < 2; ++cs) {
    const int s0 = (blockIdx.x * 2 + cs) * 64;
    if (cs) __syncthreads();  // protect LDS before restage
#pragma unroll
    for (int c = 0; c < 2; ++c) {
      int L = tid + c * 256;
      int srow = L >> 3;            // 0..63
      int col = (L & 7) * 8;        // 0..56
      size_t g = (size_t)(b * SS + s0 + srow) * DD + h * HDIM + col;
      uint4 xraw = *reinterpret_cast<const uint4*>(Xb + g);
      uint4 yraw = *reinterpret_cast<const uint4*>(Yb + g);
      float m = (am[b * SS + s0 + srow] >= 0.f) ? 1.f : 0.f;
      unsigned int xw[4] = {xraw.x, xraw.y, xraw.z, xraw.w};
      unsigned int yw[4] = {yraw.x, yraw.y, yraw.z, yraw.w};
#pragma unroll
      for (int q = 0; q < 4; ++q) {
        sX[srow * 68 + col + 2 * q]     = m * bf2f((u16)(xw[q] & 0xffffu));
        sX[srow * 68 + col + 2 * q + 1] = m * bf2f((u16)(xw[q] >> 16));
        sY[srow * 68 + col + 2 * q]     = bf2f((u16)(yw[q] & 0xffffu));
        sY[srow * 68 + col + 2 * q + 1] = bf2f((u16)(yw[q] >> 16));
      }
    }
    __syncthreads();
    for (int s = 0; s < 64; ++s) {
      float4 xx = *reinterpret_cast<const float4*>(&sX[s * 68 + e0]);
      float4 yy = *reinterpret_cast<const float4*>(&sY[s * 68 + d0]);
      float xa[4] = {xx.x, xx.y, xx.z, xx.w};
      float ya[4] = {yy.x, yy.y, yy.z, yy.w};
#pragma unroll
      for (int i = 0; i < 4; ++i)
#pragma unroll
        for (int j = 0; j < 4; ++j) acc[i][j] += xa[i] * ya[j];
    }
  }
  float* outp = mpart + ((size_t)(blockIdx.x * 32 + bh)) * 4096;
#pragma unroll
  for (int i = 0; i < 4; ++i) {
    float4 o = {acc[i][0], acc[i][1], acc[i][2], acc[i][3]};
    *reinterpret_cast<float4*>(&outp[(e0 + i) * 64 + d0]) = o;
  }
}

// ---------------- kernel 4: ctx[m, h*64+d] = sum_e Q[m, h*64+e] * M[e,d]  (MFMA) ----------------
// Inline 16-partial reduction during M staging (mpart 8 MB, L2/L3-resident) -> one fewer
// dispatch than the r1 split reduce+ctx. sMT holds M^T bf16 [64][72] (4-way alias pad).
__global__ __launch_bounds__(256) void ctx_kernel(
    const u16* __restrict__ Qb, const float* __restrict__ mpart, float* __restrict__ Out) {
  __shared__ u16 sMT[64 * 72];
  const int m0 = blockIdx.x * 128;
  const int h = blockIdx.y;
  const int b = m0 >> 11;         // 128-row tiles never cross the batch boundary
  const int bh = b * HH + h;
  const int tid = threadIdx.x;
#pragma unroll
  for (int c = 0; c < 4; ++c) {
    int L4 = c * 256 + tid;       // float4 index 0..1023 within the 64x64 M^T block
    float4 s = {0.f, 0.f, 0.f, 0.f};
#pragma unroll
    for (int pc = 0; pc < 16; ++pc) {
      const float4* p4 = reinterpret_cast<const float4*>(mpart + ((size_t)(pc * 32 + bh)) * 4096);
      float4 t = p4[L4];
      s.x += t.x; s.y += t.y; s.z += t.z; s.w += t.w;
    }
    int d = L4 >> 4, e = (L4 & 15) * 4;
    ushort4 o = {f2bf(s.x), f2bf(s.y), f2bf(s.z), f2bf(s.w)};
    *reinterpret_cast<ushort4*>(&sMT[d * 72 + e]) = o;
  }
  __syncthreads();
  const int lane = tid & 63, wave = tid >> 6;
  const int l32 = lane & 31, khalf = lane >> 5;
  const int arow = m0 + wave * 32 + l32;
  const u16* qrow = Qb + (size_t)arow * DD + h * HDIM + khalf * 8;
  bf16x8 af[4], bfr[2][4];
#pragma unroll
  for (int k0 = 0; k0 < 4; ++k0) {
    af[k0] = *reinterpret_cast<const bf16x8*>(qrow + k0 * 16);
#pragma unroll
    for (int j = 0; j < 2; ++j)
      bfr[j][k0] = *reinterpret_cast<const bf16x8*>(
          &sMT[(j * 32 + l32) * 72 + k0 * 16 + khalf * 8]);
  }
  floatx16 acc[2] = {};
#pragma unroll
  for (int j = 0; j < 2; ++j)
#pragma unroll
    for (int k0 = 0; k0 < 4; ++k0)
      acc[j] = __builtin_amdgcn_mfma_f32_32x32x16_bf16(af[k0], bfr[j][k0], acc[j], 0, 0, 0);
  // C/D layout: col = lane&31, row = (reg&3)+8*(reg>>2)+4*khalf
#pragma unroll
  for (int j = 0; j < 2; ++j) {
    int col = h * HDIM + j * 32 + l32;
#pragma unroll
    for (int reg = 0; reg < 16; ++reg) {
      int r = m0 + wave * 32 + (reg & 3) + 8 * (reg >> 2) + 4 * khalf;
      Out[(size_t)r * DD + col] = acc[j][reg];
    }
  }
}

extern "C" void kernel_launch(void* const* d_in, const int* in_sizes, int n_in,
                              void* d_out, int out_size, void* d_ws, size_t ws_size,
                              hipStream_t stream) {
  const float* hs = (const float*)d_in[0];
  const float* am = (const float*)d_in[1];
  const float* wq = (const float*)d_in[2];
  const float* bq = (const float*)d_in[3];
  const float* wk = (const float*)d_in[4];
  const float* bk = (const float*)d_in[5];
  const float* wv = (const float*)d_in[6];
  const float* bv = (const float*)d_in[7];
  float* out = (float*)d_out;
  char* ws = (char*)d_ws;

  // workspace layout (bytes), all 16B-aligned; total ~48 MB
  u16* hs_b = (u16*)(ws);                  // 8 MiB  [4096,1024] bf16
  u16* wq_b = (u16*)(ws + 8388608);        // 2 MiB
  u16* wk_b = (u16*)(ws + 10485760);       // 2 MiB
  u16* wv_b = (u16*)(ws + 12582912);       // 2 MiB
  u16* q_b  = (u16*)(ws + 14680064);       // 8 MiB
  u16* k_b  = (u16*)(ws + 23068672);       // 8 MiB
  u16* v_b  = (u16*)(ws + 31457280);       // 8 MiB
  float* mpart = (float*)(ws + 39845888);  // 8 MiB [16 pc][32 bh][64][64] f32 (M^T partials)

  cast_to_bf16<<<7168, 256, 0, stream>>>(hs, wq, wk, wv, hs_b, wq_b, wk_b, wv_b);
  qkv_gemm_kernel<<<dim3(24, 32), 256, 0, stream>>>(hs_b, wq_b, wk_b, wv_b,
                                                    bq, bk, bv, q_b, k_b, v_b);
  // X=V, Y=K -> partials hold M^T
  m_partial_kernel<<<dim3(16, 32), 256, 0, stream>>>(v_b, k_b, am, mpart);
  ctx_kernel<<<dim3(32, 16), 256, 0, stream>>>(q_b, mpart, out);
}

// Round 7
// 151.531 us; speedup vs baseline: 1.0751x; 1.0133x over previous
//
#include <hip/hip_runtime.h>

#define BB 2
#define SS 2048
#define DD 1024
#define HH 16
#define HDIM 64
#define MTOT 4096  // B*S

typedef unsigned short u16;
typedef __bf16 bf16_t;
typedef bf16_t bf16x8 __attribute__((ext_vector_type(8)));
typedef float floatx4 __attribute__((ext_vector_type(4)));
typedef float floatx16 __attribute__((ext_vector_type(16)));

__device__ __forceinline__ float bf2f(u16 u) {
  union { unsigned int i; float f; } x;
  x.i = ((unsigned int)u) << 16;
  return x.f;
}
// round-to-nearest-even f32 -> bf16 (finite inputs only)
__device__ __forceinline__ u16 f2bf(float f) {
  union { float f; unsigned int i; } x;
  x.f = f;
  unsigned int r = x.i + 0x7fffu + ((x.i >> 16) & 1u);
  return (u16)(r >> 16);
}

// async global->LDS, 16B per lane. LDS dest = wave-uniform base + lane*16.
__device__ __forceinline__ void gload16(const u16* g, u16* l) {
  __builtin_amdgcn_global_load_lds(
      (const __attribute__((address_space(1))) unsigned int*)g,
      (__attribute__((address_space(3))) unsigned int*)l, 16, 0, 0);
}

// ---------------- kernel 1: fp32 -> bf16 cast of hs, Wq, Wk, Wv ----------------
__global__ __launch_bounds__(256) void cast_to_bf16(
    const float* __restrict__ hs, const float* __restrict__ wq,
    const float* __restrict__ wk, const float* __restrict__ wv,
    u16* __restrict__ hs_b, u16* __restrict__ wq_b,
    u16* __restrict__ wk_b, u16* __restrict__ wv_b) {
  int fid = blockIdx.x * 256 + threadIdx.x;  // 0 .. 1835007
  const float* src;
  u16* dst;
  int local;
  if (fid < 1048576) { src = hs; dst = hs_b; local = fid; }
  else if (fid < 1310720) { src = wq; dst = wq_b; local = fid - 1048576; }
  else if (fid < 1572864) { src = wk; dst = wk_b; local = fid - 1310720; }
  else { src = wv; dst = wv_b; local = fid - 1572864; }
  float4 v = reinterpret_cast<const float4*>(src)[local];
  ushort4 o;
  o.x = f2bf(v.x); o.y = f2bf(v.y); o.z = f2bf(v.z); o.w = f2bf(v.w);
  reinterpret_cast<ushort4*>(dst)[local] = o;
}

// ---------------- kernel 2: fused QKV projection, r0 tile + 3-buffer 2-deep pipeline ----------------
// C[m,n] = sum_k A[m,k]*W[n,k] + bias[n].  A [4096,1024] bf16, W [1024,1024] bf16 (B^T).
// r6 post-mortem: per-step cost is DRAIN LATENCY (BK32 vs BK64 identical; conflict-halving
// identical). Fix: 2-deep prefetch at UNCHANGED occupancy:
//  - 3 LDS buffers x (8K A + 8K B) = 48 KiB -> still ~3 blocks/CU (r5's 96 KiB killed it).
//  - stage tile t+2 during compute of tile t; end-of-iter wait = s_waitcnt vmcnt(4):
//    buf[t+1]'s 4 loads (issued a full compute-phase x2 ago, ~800-1000 cy cover >= HBM
//    latency) are done, buf[t+2]'s 4 stay in flight. Never vmcnt(0) until the tail (t=30).
//  - raw asm s_barrier (NOT __syncthreads) so no compiler-inserted vmcnt(0) drain.
//  - grid stays dim3(24,32) x-major (known-good FETCH ~36 MB); no swizzle (r6: conflicts
//    proven off the critical path); BK=32, 32x32x16 MFMA, r0's verified C/D layout.
#define BKK 32
__global__ __launch_bounds__(256) void qkv_gemm_kernel(
    const u16* __restrict__ A,
    const u16* __restrict__ Wq, const u16* __restrict__ Wk, const u16* __restrict__ Wv,
    const float* __restrict__ bq, const float* __restrict__ bk, const float* __restrict__ bv,
    u16* __restrict__ Qo, u16* __restrict__ Ko, u16* __restrict__ Vo) {
  __shared__ u16 sA[3][128 * BKK];  // 3 x 8 KiB
  __shared__ u16 sB[3][128 * BKK];  // 3 x 8 KiB  (48 KiB total)
  const int mt = blockIdx.y, ntall = blockIdx.x;
  const int seg = ntall >> 3, nt = ntall & 7;
  const u16* Wp = (seg == 0) ? Wq : (seg == 1) ? Wk : Wv;
  const float* bp = (seg == 0) ? bq : (seg == 1) ? bk : bv;
  u16* Out = (seg == 0) ? Qo : (seg == 1) ? Ko : Vo;
  const int m0 = mt * 128, n0 = nt * 128;
  const int tid = threadIdx.x;
  const int lane = tid & 63, wave = tid >> 6;
  const int wm = (wave >> 1) * 64, wn = (wave & 1) * 64;
  const int l32 = lane & 31, khalf = lane >> 5;
  // staging coords (r0): per wave 2 chunks of 1024B; lane covers 16B, lane-linear LDS.
  const int srow0 = wave * 32 + (lane >> 2);
  const int scol = (lane & 3) * 8;

// 4 gload16 instructions per thread per STAGE -> vmcnt counts in units of 4.
#define STAGE(buf, kbase)                                                    \
  {                                                                          \
    _Pragma("unroll") for (int c = 0; c < 2; ++c) {                          \
      int r = srow0 + c * 16;                                                \
      gload16(A + (size_t)(m0 + r) * DD + (kbase) + scol,                    \
              sA[buf] + r * BKK + scol);                                     \
      gload16(Wp + (size_t)(n0 + r) * DD + (kbase) + scol,                   \
              sB[buf] + r * BKK + scol);                                     \
    }                                                                        \
  }

  floatx16 acc[2][2] = {};
  STAGE(0, 0);
  STAGE(1, BKK);
  asm volatile("s_waitcnt vmcnt(4)" ::: "memory");  // buf0 landed; buf1 in flight
  asm volatile("s_barrier" ::: "memory");

  int cur = 0;
  for (int t = 0; t < 32; ++t) {
    // issue 2-ahead prefetch first: overwrites the buffer whose readers finished at the
    // barrier ending iter t-1; its drain is deferred to the END of iter t+1 (2-phase cover).
    if (t < 30) {
      int nb = cur + 2;
      if (nb >= 3) nb -= 3;
      STAGE(nb, (t + 2) * BKK);
    }
    const u16* pA = sA[cur];
    const u16* pB = sB[cur];
#pragma unroll
    for (int kk = 0; kk < 2; ++kk) {
      bf16x8 af[2], bfr[2];
#pragma unroll
      for (int i = 0; i < 2; ++i)
        af[i] = *reinterpret_cast<const bf16x8*>(pA + (wm + i * 32 + l32) * BKK + kk * 16 + khalf * 8);
#pragma unroll
      for (int j = 0; j < 2; ++j)
        bfr[j] = *reinterpret_cast<const bf16x8*>(pB + (wn + j * 32 + l32) * BKK + kk * 16 + khalf * 8);
#pragma unroll
      for (int i = 0; i < 2; ++i)
#pragma unroll
        for (int j = 0; j < 2; ++j)
          acc[i][j] = __builtin_amdgcn_mfma_f32_32x32x16_bf16(af[i], bfr[j], acc[i][j], 0, 0, 0);
    }
    // counted wait: own outstanding = buf[t+1](4) + buf[t+2](4); vmcnt(4) -> buf[t+1] done,
    // buf[t+2] stays in flight. Barrier makes it block-wide. Tail: t=30 drains the last stage.
    if (t < 30) asm volatile("s_waitcnt vmcnt(4)" ::: "memory");
    else if (t == 30) asm volatile("s_waitcnt vmcnt(0)" ::: "memory");
    if (t < 31) asm volatile("s_barrier" ::: "memory");
    cur = (cur < 2) ? cur + 1 : 0;
  }
#undef STAGE

  // epilogue: C/D layout col=lane&31, row=(reg&3)+8*(reg>>2)+4*(lane>>5)
#pragma unroll
  for (int j = 0; j < 2; ++j) {
    int col = n0 + wn + j * 32 + l32;
    float bias = bp[col];
#pragma unroll
    for (int i = 0; i < 2; ++i) {
#pragma unroll
      for (int reg = 0; reg < 16; ++reg) {
        int row = m0 + wm + i * 32 + (reg & 3) + 8 * (reg >> 2) + 4 * khalf;
        Out[(size_t)row * DD + col] = f2bf(acc[i][j][reg] + bias);
      }
    }
  }
}

// ---------------- kernel 3: mpart[pc][bh][d][e] = sum_{s in chunk pc} mask[s]*V[s,d]*K[s,e] ----------------
// 8 superchunks of 256 s-rows (4 sub-tiles of 64) x 32 bh = 256 blocks (r0-proven shape).
__global__ __launch_bounds__(256) void m_partial_kernel(
    const u16* __restrict__ Xb, const u16* __restrict__ Yb,
    const float* __restrict__ am, float* __restrict__ mpart) {
  __shared__ float sX[64 * 68];
  __shared__ float sY[64 * 68];
  const int bh = blockIdx.y;     // 0..31
  const int b = bh >> 4, h = bh & 15;
  const int tid = threadIdx.x;
  const int e0 = (tid & 15) * 4, d0 = (tid >> 4) * 4;
  float acc[4][4] = {};
  for (int cs = 0; cs < 4; ++cs) {
    const int s0 = (blockIdx.x * 4 + cs) * 64;
    if (cs) __syncthreads();  // protect LDS before restage
#pragma unroll
    for (int c = 0; c < 2; ++c) {
      int L = tid + c * 256;
      int srow = L >> 3;            // 0..63
      int col = (L & 7) * 8;        // 0..56
      size_t g = (size_t)(b * SS + s0 + srow) * DD + h * HDIM + col;
      uint4 xraw = *reinterpret_cast<const uint4*>(Xb + g);
      uint4 yraw = *reinterpret_cast<const uint4*>(Yb + g);
      float m = (am[b * SS + s0 + srow] >= 0.f) ? 1.f : 0.f;
      unsigned int xw[4] = {xraw.x, xraw.y, xraw.z, xraw.w};
      unsigned int yw[4] = {yraw.x, yraw.y, yraw.z, yraw.w};
#pragma unroll
      for (int q = 0; q < 4; ++q) {
        sX[srow * 68 + col + 2 * q]     = m * bf2f((u16)(xw[q] & 0xffffu));
        sX[srow * 68 + col + 2 * q + 1] = m * bf2f((u16)(xw[q] >> 16));
        sY[srow * 68 + col + 2 * q]     = bf2f((u16)(yw[q] & 0xffffu));
        sY[srow * 68 + col + 2 * q + 1] = bf2f((u16)(yw[q] >> 16));
      }
    }
    __syncthreads();
    for (int s = 0; s < 64; ++s) {
      float4 xx = *reinterpret_cast<const float4*>(&sX[s * 68 + e0]);
      float4 yy = *reinterpret_cast<const float4*>(&sY[s * 68 + d0]);
      float xa[4] = {xx.x, xx.y, xx.z, xx.w};
      float ya[4] = {yy.x, yy.y, yy.z, yy.w};
#pragma unroll
      for (int i = 0; i < 4; ++i)
#pragma unroll
        for (int j = 0; j < 4; ++j) acc[i][j] += xa[i] * ya[j];
    }
  }
  float* outp = mpart + ((size_t)(blockIdx.x * 32 + bh)) * 4096;
#pragma unroll
  for (int i = 0; i < 4; ++i) {
    float4 o = {acc[i][0], acc[i][1], acc[i][2], acc[i][3]};
    *reinterpret_cast<float4*>(&outp[(e0 + i) * 64 + d0]) = o;
  }
}

// ---------------- kernel 4: ctx[m, h*64+d] = sum_e Q[m, h*64+e] * M[e,d]  (MFMA) ----------------
// Inline 8-partial reduction during M staging (mpart 4 MB, L2-resident).
__global__ __launch_bounds__(256) void ctx_kernel(
    const u16* __restrict__ Qb, const float* __restrict__ mpart, float* __restrict__ Out) {
  __shared__ u16 sMT[64 * 72];
  const int m0 = blockIdx.x * 128;
  const int h = blockIdx.y;
  const int b = m0 >> 11;         // 128-row tiles never cross the batch boundary
  const int bh = b * HH + h;
  const int tid = threadIdx.x;
#pragma unroll
  for (int c = 0; c < 4; ++c) {
    int L4 = c * 256 + tid;       // float4 index 0..1023 within the 64x64 M^T block
    float4 s = {0.f, 0.f, 0.f, 0.f};
#pragma unroll
    for (int pc = 0; pc < 8; ++pc) {
      const float4* p4 = reinterpret_cast<const float4*>(mpart + ((size_t)(pc * 32 + bh)) * 4096);
      float4 t = p4[L4];
      s.x += t.x; s.y += t.y; s.z += t.z; s.w += t.w;
    }
    int d = L4 >> 4, e = (L4 & 15) * 4;
    ushort4 o = {f2bf(s.x), f2bf(s.y), f2bf(s.z), f2bf(s.w)};
    *reinterpret_cast<ushort4*>(&sMT[d * 72 + e]) = o;
  }
  __syncthreads();
  const int lane = tid & 63, wave = tid >> 6;
  const int l32 = lane & 31, khalf = lane >> 5;
  const int arow = m0 + wave * 32 + l32;
  const u16* qrow = Qb + (size_t)arow * DD + h * HDIM + khalf * 8;
  bf16x8 af[4], bfr[2][4];
#pragma unroll
  for (int k0 = 0; k0 < 4; ++k0) {
    af[k0] = *reinterpret_cast<const bf16x8*>(qrow + k0 * 16);
#pragma unroll
    for (int j = 0; j < 2; ++j)
      bfr[j][k0] = *reinterpret_cast<const bf16x8*>(
          &sMT[(j * 32 + l32) * 72 + k0 * 16 + khalf * 8]);
  }
  floatx16 acc[2] = {};
#pragma unroll
  for (int j = 0; j < 2; ++j)
#pragma unroll
    for (int k0 = 0; k0 < 4; ++k0)
      acc[j] = __builtin_amdgcn_mfma_f32_32x32x16_bf16(af[k0], bfr[j][k0], acc[j], 0, 0, 0);
  // C/D layout: col = lane&31, row = (reg&3)+8*(reg>>2)+4*khalf
#pragma unroll
  for (int j = 0; j < 2; ++j) {
    int col = h * HDIM + j * 32 + l32;
#pragma unroll
    for (int reg = 0; reg < 16; ++reg) {
      int r = m0 + wave * 32 + (reg & 3) + 8 * (reg >> 2) + 4 * khalf;
      Out[(size_t)r * DD + col] = acc[j][reg];
    }
  }
}

extern "C" void kernel_launch(void* const* d_in, const int* in_sizes, int n_in,
                              void* d_out, int out_size, void* d_ws, size_t ws_size,
                              hipStream_t stream) {
  const float* hs = (const float*)d_in[0];
  const float* am = (const float*)d_in[1];
  const float* wq = (const float*)d_in[2];
  const float* bq = (const float*)d_in[3];
  const float* wk = (const float*)d_in[4];
  const float* bk = (const float*)d_in[5];
  const float* wv = (const float*)d_in[6];
  const float* bv = (const float*)d_in[7];
  float* out = (float*)d_out;
  char* ws = (char*)d_ws;

  // workspace layout (bytes), all 16B-aligned; total ~44 MB
  u16* hs_b = (u16*)(ws);                  // 8 MiB  [4096,1024] bf16
  u16* wq_b = (u16*)(ws + 8388608);        // 2 MiB
  u16* wk_b = (u16*)(ws + 10485760);       // 2 MiB
  u16* wv_b = (u16*)(ws + 12582912);       // 2 MiB
  u16* q_b  = (u16*)(ws + 14680064);       // 8 MiB
  u16* k_b  = (u16*)(ws + 23068672);       // 8 MiB
  u16* v_b  = (u16*)(ws + 31457280);       // 8 MiB
  float* mpart = (float*)(ws + 39845888);  // 4 MiB [8 pc][32 bh][64][64] f32 (M^T partials)

  cast_to_bf16<<<7168, 256, 0, stream>>>(hs, wq, wk, wv, hs_b, wq_b, wk_b, wv_b);
  qkv_gemm_kernel<<<dim3(24, 32), 256, 0, stream>>>(hs_b, wq_b, wk_b, wv_b,
                                                    bq, bk, bv, q_b, k_b, v_b);
  // X=V, Y=K -> partials hold M^T
  m_partial_kernel<<<dim3(8, 32), 256, 0, stream>>>(v_b, k_b, am, mpart);
  ctx_kernel<<<dim3(32, 16), 256, 0, stream>>>(q_b, mpart, out);
}